// Round 1
// baseline (166.025 us; speedup 1.0000x reference)
//
#include <hip/hip_runtime.h>
#include <hip/hip_bf16.h>
#include <hip/hip_cooperative_groups.h>

namespace cg = cooperative_groups;

// 3x3 VALID conv via bf16 MFMA implicit GEMM.
// x: (64,224,224) fp32, w: (128,64,3,3) fp32, out: (128,222,222) fp32.
//
// R10: single cooperative launch. The 3-kernel pipeline's device work models
// at ~15-25 us vs 88.6 us measured -> suspect inter-dispatch drain/launch
// overhead. Fuse: phase 1 grid-strides the weight transform (288 units) +
// x transpose (904 units); one grid.sync(); phase 2 = R9 conv body verbatim
// (unit = old blockIdx, 392 units). 512 blocks x 256 thr = exactly the
// 2-blocks/CU LDS residency bound (65,344 B/block); __launch_bounds__(256,2)
// caps VGPR at 256 so cooperative residency is guaranteed.
// Transpose LDS tile (8,704 B) aliases conv xs (48,960 B).

#define H_IN   224
#define W_IN   224
#define C_OUT  128
#define H_OUT  222
#define W_OUT  222
#define XP     226   // padded spatial extent of xt
#define CPAD   72    // padded c stride in conv x-LDS (144B = 16B*9, bank-floor)
#define TW     68    // padded w stride in transpose LDS

#define PREP_W_UNITS 288    // 288*256 = 73,728 weight elements
#define PREP_UNITS   1192   // 288 w-units + 904 transpose units (226 rows x 4)
#define CONV_UNITS   392    // 7 x 28 x 2
#define GRID_BLKS    512    // 2 blocks/CU x 256 CU (LDS-limited residency)

typedef __attribute__((ext_vector_type(8)))  short bf16x8;
typedef __attribute__((ext_vector_type(16))) float f32x16;

static __device__ __forceinline__ unsigned short f2bs(float f) {
    union { __hip_bfloat16 h; unsigned short u; } cv;
    cv.h = __float2bfloat16(f);
    return cv.u;
}

__global__ __launch_bounds__(256, 2)
void fused_conv_kernel(const float* __restrict__ x, const float* __restrict__ w,
                       __hip_bfloat16* __restrict__ xt, __hip_bfloat16* __restrict__ wt,
                       float* __restrict__ out)
{
    __shared__ __align__(16) __hip_bfloat16 xs[10 * 34 * CPAD];   // 48,960 B
    __shared__ __align__(16) __hip_bfloat16 wsb[2][8 * 64 * 8];   // 2 x 8,192 B
    const int tid = threadIdx.x;

    // ---------------- Phase 1: weight transform + x transpose ----------------
    for (int u = blockIdx.x; u < PREP_UNITS; u += GRID_BLKS) {
        if (u < PREP_W_UNITS) {
            // wt layout: [ij][kstep(=c>>3)][co][c&7] -> A-reads lane-contiguous.
            int idx = u * 256 + tid;
            int ij  = idx >> 13;
            int rem = idx & 8191;
            int co  = rem >> 6;
            int c   = rem & 63;
            wt[((ij * 8 + (c >> 3)) * 128 + co) * 8 + (c & 7)] =
                __float2bfloat16(w[(co * 64 + c) * 9 + ij]);
        } else {
            unsigned short* tile = (unsigned short*)xs;   // 64*TW*2 = 8,704 B alias
            const int ux = u - PREP_W_UNITS;              // 0..903
            const int h  = ux >> 2;                       // 0..225
            const int w0 = (ux & 3) * 64;                 // 0,64,128,192
            __syncthreads();   // tile reuse across grid-stride iterations

            // Coalesced float4 reads along w; zeros for padded h/w.
            {
                const int wq = (tid & 15) * 4;            // 0..60
                const int c0 = tid >> 4;                  // 0..15
                #pragma unroll
                for (int p = 0; p < 4; ++p) {
                    const int c  = c0 + p * 16;
                    const int wg = w0 + wq;
                    float4 v = make_float4(0.f, 0.f, 0.f, 0.f);
                    if (h < H_IN && wg < W_IN)            // W_IN%4==0 -> all-or-nothing
                        v = *(const float4*)(x + ((size_t)c * H_IN + h) * W_IN + wg);
                    ushort4 b;
                    b.x = f2bs(v.x); b.y = f2bs(v.y); b.z = f2bs(v.z); b.w = f2bs(v.w);
                    *(ushort4*)(tile + c * TW + wq) = b;
                }
            }
            __syncthreads();

            // Gather 16 c per thread, contiguous 16B/lane stores to xt.
            {
                const int wl = tid >> 2;                  // 0..63
                const int cq = (tid & 3) * 16;            // 0,16,32,48
                const int wg = w0 + wl;
                if (wg < XP) {
                    alignas(16) unsigned short r[16];
                    #pragma unroll
                    for (int k = 0; k < 16; ++k)
                        r[k] = tile[(cq + k) * TW + wl];
                    float4* d = (float4*)((unsigned short*)xt + ((size_t)h * XP + wg) * 64 + cq);
                    d[0] = ((const float4*)r)[0];
                    d[1] = ((const float4*)r)[1];
                }
            }
        }
    }

    cg::this_grid().sync();   // xt/wt fully written + device-visible

    // ---------------- Phase 2: conv (unit = old block) ----------------
    const int u = blockIdx.x;
    if (u >= CONV_UNITS) return;
    const int bz  = u / 196;
    const int rm  = u - bz * 196;
    const int by  = rm / 7;
    const int bx  = rm - by * 7;
    const int ow0 = bx * 32;
    const int oh0 = by * 8;
    const int co0 = bz * 64;

    // Stage x tile: rows oh0..oh0+9, cols ow0..ow0+33, all 64 c (bf16).
    for (int q = tid; q < 10 * 34 * 8; q += 256) {
        int sub = q & 7;
        int pix = q >> 3;
        int row = pix / 34;
        int wc  = pix - row * 34;
        *(float4*)(xs + (row * 34 + wc) * CPAD + sub * 8) =
            *(const float4*)(xt + ((oh0 + row) * XP + (ow0 + wc)) * 64 + sub * 8);
    }
    // Stage tap 0 weights (this block's 64 co): 8,192 B, lane-contiguous.
    #pragma unroll
    for (int k = 0; k < 2; ++k) {
        int q  = k * 256 + tid;          // 512 chunks of 16B
        int ks = q >> 6;                 // kstep 0..7
        int cc = q & 63;                 // co 0..63
        *(float4*)(&wsb[0][(ks * 64 + cc) * 8]) =
            *(const float4*)(wt + ((0 * 8 + ks) * 128 + co0 + cc) * 8);
    }
    __syncthreads();

    const int wave = tid >> 6;
    const int lane = tid & 63;
    const int n    = lane & 31;     // A: co offset; B: ow offset; D: col
    const int h    = lane >> 5;     // k-half selector
    const int r0   = wave * 2;      // this wave's 2 output rows

    f32x16 acc[2][2] = {};          // [mi][ni]

    #pragma unroll
    for (int p = 0; p < 9; ++p) {   // tap index = i*3 + jj
        const int i  = p / 3;
        const int jj = p - i * 3;
        const int cb = p & 1;

        // Prefetch next tap into the other buffer (loads issued before compute,
        // LDS writes land before the barrier; global latency hidden by MFMAs).
        float4 pf[2];
        int ks0 = 0, cc0 = 0, ks1 = 0, cc1 = 0;
        if (p < 8) {
            #pragma unroll
            for (int k = 0; k < 2; ++k) {
                int q  = k * 256 + tid;
                int ks = q >> 6;
                int cc = q & 63;
                pf[k] = *(const float4*)(wt + (((p + 1) * 8 + ks) * 128 + co0 + cc) * 8);
                if (k == 0) { ks0 = ks; cc0 = cc; } else { ks1 = ks; cc1 = cc; }
            }
        }

        // Compute tap p: 4 k-steps, mi=2 x ni=2 register tile.
        #pragma unroll
        for (int t = 0; t < 4; ++t) {
            bf16x8 afr[2], bfr[2];
            #pragma unroll
            for (int mi = 0; mi < 2; ++mi)
                afr[mi] = *(const bf16x8*)(&wsb[cb][((t * 2 + h) * 64 + mi * 32 + n) * 8]);
            #pragma unroll
            for (int ni = 0; ni < 2; ++ni)
                bfr[ni] = *(const bf16x8*)(xs +
                    ((i + r0 + ni) * 34 + n + jj) * CPAD + t * 16 + h * 8);
            #pragma unroll
            for (int mi = 0; mi < 2; ++mi)
                #pragma unroll
                for (int ni = 0; ni < 2; ++ni)
                    acc[mi][ni] = __builtin_amdgcn_mfma_f32_32x32x16_bf16(
                        afr[mi], bfr[ni], acc[mi][ni], 0, 0, 0);
        }

        if (p < 8) {
            *(float4*)(&wsb[1 - cb][(ks0 * 64 + cc0) * 8]) = pf[0];
            *(float4*)(&wsb[1 - cb][(ks1 * 64 + cc1) * 8]) = pf[1];
        }
        __syncthreads();   // next iter reads wsb[1-cb]; iter after overwrites wsb[cb]
    }

    // Epilogue: lanes 0..31 = 32 consecutive ow -> 128B full-line stores.
    #pragma unroll
    for (int mi = 0; mi < 2; ++mi) {
        #pragma unroll
        for (int ni = 0; ni < 2; ++ni) {
            const int oh = oh0 + r0 + ni;
            const int ow = ow0 + n;
            if (oh < H_OUT && ow < W_OUT) {
                #pragma unroll
                for (int r = 0; r < 16; ++r) {
                    int co = co0 + mi * 32 + (r & 3) + 8 * (r >> 2) + 4 * h;
                    out[(size_t)co * (H_OUT * W_OUT) + oh * W_OUT + ow] = acc[mi][ni][r];
                }
            }
        }
    }
}

extern "C" void kernel_launch(void* const* d_in, const int* in_sizes, int n_in,
                              void* d_out, int out_size, void* d_ws, size_t ws_size,
                              hipStream_t stream)
{
    const float* x = (const float*)d_in[0];
    const float* w = (const float*)d_in[1];
    float* out     = (float*)d_out;

    __hip_bfloat16* xt = (__hip_bfloat16*)d_ws;                      // 226*226*64*2 B
    __hip_bfloat16* wt = (__hip_bfloat16*)((char*)d_ws + (size_t)XP * XP * 64 * 2);

    void* args[] = { (void*)&x, (void*)&w, (void*)&xt, (void*)&wt, (void*)&out };
    hipLaunchCooperativeKernel(fused_conv_kernel, dim3(GRID_BLKS), dim3(256),
                               args, 0, stream);
}

// Round 2
// 88.009 us; speedup vs baseline: 1.8865x; 1.8865x over previous
//
#include <hip/hip_runtime.h>
#include <hip/hip_bf16.h>

// 3x3 VALID conv via bf16 MFMA implicit GEMM.
// x: (64,224,224) fp32, w: (128,64,3,3) fp32, out: (128,222,222) fp32.
//
// R11: back to 3 regular launches (R10 showed cooperative launch costs ~30us
// in-harness and the fused kernel stalled at 91us with all pipes <8% busy).
// Conv rebuilt barrier-free: weights are L2-resident (147KB) and the A-fragment
// read is a coalesced 64-lane x 16B = 1KB transaction, so read them DIRECTLY
// from global instead of LDS double-buffering -> no per-tap __syncthreads.
// Single barrier after xs staging; 72 unrolled {2 gload + 1 ds_read + 2 MFMA}
// steps pipeline freely. Block shrunk to 64co x 4oh x 32ow (LDS 29.4KB,
// grid 784) -> ~3 blocks/CU, 12-16 waves/CU for latency hiding.
// A: m=lane&31, k=(lane>>5)*8+j. B: n=lane&31. D: col=lane&31,
// row=(reg&3)+8*(reg>>2)+4*(lane>>5)  [m74/m101-verified].

#define H_IN   224
#define W_IN   224
#define C_OUT  128
#define H_OUT  222
#define W_OUT  222
#define XP     226   // padded spatial extent of xt
#define CPAD   72    // padded c stride in conv x-LDS (144B = 16B*9, bank-floor)
#define TW     68    // padded w stride in transpose LDS

typedef __attribute__((ext_vector_type(8)))  short bf16x8;
typedef __attribute__((ext_vector_type(16))) float f32x16;

static __device__ __forceinline__ unsigned short f2bs(float f) {
    union { __hip_bfloat16 h; unsigned short u; } cv;
    cv.h = __float2bfloat16(f);
    return cv.u;
}

// wt layout: [ij][kstep(=c>>3)][co][c&7]  -> A-fragment reads lane-contiguous.
__global__ __launch_bounds__(256)
void transform_w_kernel(const float* __restrict__ w, __hip_bfloat16* __restrict__ wt)
{
    int idx = blockIdx.x * 256 + threadIdx.x;     // 9*128*64 = 73,728
    if (idx < 9 * 128 * 64) {
        int ij  = idx >> 13;
        int rem = idx & 8191;
        int co  = rem >> 6;
        int c   = rem & 63;
        wt[((ij * 8 + (c >> 3)) * 128 + co) * 8 + (c & 7)] =
            __float2bfloat16(w[(co * 64 + c) * 9 + ij]);
    }
}

__global__ __launch_bounds__(256)
void transpose_x_kernel(const float* __restrict__ x, __hip_bfloat16* __restrict__ xt)
{
    __shared__ __align__(16) unsigned short tile[64 * TW];   // [c][w_local]
    const int h  = blockIdx.y;                 // 0..225
    const int w0 = blockIdx.x * 64;            // 0,64,128,192
    const int t  = threadIdx.x;

    // Phase 1: coalesced float4 reads along w; zeros for padded h/w.
    {
        const int wq = (t & 15) * 4;           // 0..60 (lanes contiguous in w)
        const int c0 = t >> 4;                 // 0..15
        #pragma unroll
        for (int p = 0; p < 4; ++p) {
            const int c  = c0 + p * 16;
            const int wg = w0 + wq;
            float4 v = make_float4(0.f, 0.f, 0.f, 0.f);
            if (h < H_IN && wg < W_IN)         // wg%4==0, W_IN%4==0 -> all-or-nothing
                v = *(const float4*)(x + ((size_t)c * H_IN + h) * W_IN + wg);
            ushort4 b;
            b.x = f2bs(v.x); b.y = f2bs(v.y); b.z = f2bs(v.z); b.w = f2bs(v.w);
            *(ushort4*)(tile + c * TW + wq) = b;   // (c*136 + wq*2) % 8 == 0
        }
    }
    __syncthreads();

    // Phase 2: gather 16 c per thread from LDS, contiguous 16B/lane stores.
    {
        const int wl = t >> 2;                 // 0..63
        const int cq = (t & 3) * 16;           // 0,16,32,48
        const int wg = w0 + wl;
        if (wg < XP) {
            alignas(16) unsigned short r[16];
            #pragma unroll
            for (int k = 0; k < 16; ++k)
                r[k] = tile[(cq + k) * TW + wl];
            float4* d = (float4*)((unsigned short*)xt + ((size_t)h * XP + wg) * 64 + cq);
            d[0] = ((const float4*)r)[0];
            d[1] = ((const float4*)r)[1];
        }
    }
}

__global__ __launch_bounds__(256, 4)
void conv_mfma_kernel(const __hip_bfloat16* __restrict__ xt,
                      const __hip_bfloat16* __restrict__ wt,
                      float* __restrict__ out)
{
    __shared__ __hip_bfloat16 xs[6 * 34 * CPAD];   // [row][wc][c]  29,376 B
    const int ow0 = blockIdx.x * 32;
    const int oh0 = blockIdx.y * 4;
    const int co0 = blockIdx.z * 64;
    const int tid = threadIdx.x;

    // Stage x tile: rows oh0..oh0+5, cols ow0..ow0+33, all 64 c (bf16).
    for (int q = tid; q < 6 * 34 * 8; q += 256) {
        int sub = q & 7;
        int pix = q >> 3;
        int row = pix / 34;
        int wc  = pix - row * 34;
        *(float4*)(xs + (row * 34 + wc) * CPAD + sub * 8) =
            *(const float4*)(xt + ((oh0 + row) * XP + (ow0 + wc)) * 64 + sub * 8);
    }
    __syncthreads();   // the ONLY barrier: xs is read-only from here on

    const int wave = tid >> 6;      // this wave's output row (0..3)
    const int lane = tid & 63;
    const int n    = lane & 31;     // A: co offset; B: ow offset; D: col
    const int h    = lane >> 5;     // k-half selector

    f32x16 acc[2] = {};             // [mi]

    #pragma unroll
    for (int p = 0; p < 9; ++p) {   // tap index = i*3 + jj
        const int i  = p / 3;
        const int jj = p - i * 3;
        #pragma unroll
        for (int t = 0; t < 4; ++t) {
            // A-fragments straight from global (L2-resident, 1KB/wave coalesced).
            bf16x8 afr[2];
            #pragma unroll
            for (int mi = 0; mi < 2; ++mi)
                afr[mi] = *(const bf16x8*)(wt +
                    (size_t)(((p * 8 + t * 2 + h) * 128 + co0 + mi * 32 + n) * 8));
            bf16x8 bfr = *(const bf16x8*)(xs +
                ((i + wave) * 34 + n + jj) * CPAD + t * 16 + h * 8);
            #pragma unroll
            for (int mi = 0; mi < 2; ++mi)
                acc[mi] = __builtin_amdgcn_mfma_f32_32x32x16_bf16(
                    afr[mi], bfr, acc[mi], 0, 0, 0);
        }
    }

    // Epilogue: lanes 0..31 = 32 consecutive ow -> 128B full-line stores.
    const int oh = oh0 + wave;
    const int ow = ow0 + n;
    if (oh < H_OUT && ow < W_OUT) {
        #pragma unroll
        for (int mi = 0; mi < 2; ++mi) {
            #pragma unroll
            for (int r = 0; r < 16; ++r) {
                int co = co0 + mi * 32 + (r & 3) + 8 * (r >> 2) + 4 * h;
                out[(size_t)co * (H_OUT * W_OUT) + oh * W_OUT + ow] = acc[mi][r];
            }
        }
    }
}

extern "C" void kernel_launch(void* const* d_in, const int* in_sizes, int n_in,
                              void* d_out, int out_size, void* d_ws, size_t ws_size,
                              hipStream_t stream)
{
    const float* x = (const float*)d_in[0];
    const float* w = (const float*)d_in[1];
    float* out     = (float*)d_out;

    __hip_bfloat16* xt = (__hip_bfloat16*)d_ws;                      // 226*226*64*2 B
    __hip_bfloat16* wt = (__hip_bfloat16*)((char*)d_ws + (size_t)XP * XP * 64 * 2);

    transform_w_kernel<<<288, 256, 0, stream>>>(w, wt);
    transpose_x_kernel<<<dim3(4, XP), 256, 0, stream>>>(x, xt);
    conv_mfma_kernel<<<dim3(7, 56, 2), 256, 0, stream>>>(xt, wt, out);
}